// Round 1
// baseline (2486.047 us; speedup 1.0000x reference)
//
#include <hip/hip_runtime.h>
#include <hip/hip_bf16.h>
#include <math.h>

// B=2, T=2048, D=2048, N=8 heads, K=1 kv-head (MQA), H=256, F=16384.
// All matmuls bf16 MFMA 16x16x32, fp32 accumulate. Output fp32.

using bf16 = __hip_bfloat16;
typedef short bf16x8 __attribute__((ext_vector_type(8)));
typedef float f32x4 __attribute__((ext_vector_type(4)));

__device__ __forceinline__ void gld_lds16(const bf16* g, bf16* l) {
    __builtin_amdgcn_global_load_lds(
        (const __attribute__((address_space(1))) void*)g,
        (__attribute__((address_space(3))) void*)l, 16, 0, 0);
}

// ---------------------------------------------------------------------------
// Generic GEMM: C[m,n] = sum_k A[m,k] * Bt[n,k]  (both K-contiguous)
// 128x128 tile, BK=32, 256 threads (4 waves, 4x4 MFMA frags each).
// Grouped swizzle (GROUP_M=8) for L2 B-panel reuse.
// epi: 0 = bf16 store, 1 = f32, 2 = f32 + residual, 3 = fused gelu-gate
// (interleaved g0/g1 columns, writes bf16 acts at col/2, ldc = F).
// ---------------------------------------------------------------------------
__global__ __launch_bounds__(256, 2)
void gemm_bt(const bf16* __restrict__ A, const bf16* __restrict__ Bm,
             void* __restrict__ Cv, const float* __restrict__ res,
             int K, int lda, int ldb, int ldc,
             long sAb, long sAn, long sBb, long sBn, long sCb, long sCn,
             int nInner, int epi)
{
    __shared__ bf16 As[128 * 32];
    __shared__ bf16 Bs[128 * 32];

    const int zb = blockIdx.z / nInner;
    const int zn = blockIdx.z - zb * nInner;
    A  += (long)zb * sAb + (long)zn * sAn;
    Bm += (long)zb * sBb + (long)zn * sBn;
    const long coff = (long)zb * sCb + (long)zn * sCn;

    // grouped swizzle: consecutive blocks walk M within a GROUP_M-row band
    const int GROUP = 8;
    const int num_n = gridDim.x, num_m = gridDim.y;
    const int pid = blockIdx.y * num_n + blockIdx.x;
    const int band = GROUP * num_n;
    const int group_id = pid / band;
    const int first_m = group_id * GROUP;
    const int gsz = min(num_m - first_m, GROUP);
    const int in_group = pid - group_id * band;
    const int pid_m = first_m + (in_group % gsz);
    const int pid_n = in_group / gsz;

    const int tid  = threadIdx.x;
    const int lane = tid & 63;
    const int wave = tid >> 6;
    const int wm = wave >> 1;
    const int wn = wave & 1;
    const int lr = lane & 15;
    const int lq = lane >> 4;

    const long m_blk = (long)pid_m * 128;
    const long n_blk = (long)pid_n * 128;

    f32x4 acc[4][4] = {};

    const int c0 = wave * 64 + lane;
    const int c1 = c0 + 256;
    const int am0 = c0 >> 2, am1 = c1 >> 2;
    const int ak0 = ((c0 & 3) ^ ((am0 >> 1) & 3)) * 8;
    const int ak1 = ((c1 & 3) ^ ((am1 >> 1) & 3)) * 8;
    const long aoff0 = (m_blk + am0) * (long)lda + ak0;
    const long aoff1 = (m_blk + am1) * (long)lda + ak1;
    const long boff0 = (n_blk + am0) * (long)ldb + ak0;
    const long boff1 = (n_blk + am1) * (long)ldb + ak1;
    bf16* lA0 = &As[(wave * 64) * 8];
    bf16* lA1 = &As[(256 + wave * 64) * 8];
    bf16* lB0 = &Bs[(wave * 64) * 8];
    bf16* lB1 = &Bs[(256 + wave * 64) * 8];

    for (int k0 = 0; k0 < K; k0 += 32) {
        gld_lds16(A + aoff0 + k0, lA0);
        gld_lds16(A + aoff1 + k0, lA1);
        gld_lds16(Bm + boff0 + k0, lB0);
        gld_lds16(Bm + boff1 + k0, lB1);
        __syncthreads();

        bf16x8 af[4], bfr[4];
        #pragma unroll
        for (int t = 0; t < 4; ++t) {
            const int mr = wm * 64 + t * 16 + lr;
            af[t]  = *(const bf16x8*)&As[(mr * 4 + (lq ^ ((mr >> 1) & 3))) * 8];
            const int nr = wn * 64 + t * 16 + lr;
            bfr[t] = *(const bf16x8*)&Bs[(nr * 4 + (lq ^ ((nr >> 1) & 3))) * 8];
        }
        #pragma unroll
        for (int mt = 0; mt < 4; ++mt)
            #pragma unroll
            for (int nt = 0; nt < 4; ++nt)
                acc[mt][nt] = __builtin_amdgcn_mfma_f32_16x16x32_bf16(
                    af[mt], bfr[nt], acc[mt][nt], 0, 0, 0);
        __syncthreads();
    }

    // epilogue: C/D layout col = lane&15, row = (lane>>4)*4 + reg
    #pragma unroll
    for (int mt = 0; mt < 4; ++mt) {
        #pragma unroll
        for (int nt = 0; nt < 4; ++nt) {
            const long col = n_blk + wn * 64 + nt * 16 + lr;
            #pragma unroll
            for (int r = 0; r < 4; ++r) {
                const long row = m_blk + wm * 64 + mt * 16 + lq * 4 + r;
                const float v = acc[mt][nt][r];
                if (epi == 0) {
                    ((bf16*)Cv)[coff + row * (long)ldc + col] = __float2bfloat16(v);
                } else if (epi == 1) {
                    ((float*)Cv)[coff + row * (long)ldc + col] = v;
                } else if (epi == 2) {
                    ((float*)Cv)[coff + row * (long)ldc + col] =
                        v + res[row * (long)ldc + col];
                } else {
                    // fused gelu-gate: even col = g0, odd col = g1 (same f)
                    const float pv = __shfl_xor(v, 1, 64);
                    const float g0 = (lr & 1) ? pv : v;
                    const float g1 = (lr & 1) ? v : pv;
                    const float u = g0 + 0.044715f * g0 * g0 * g0;
                    const float act = g0 / (1.f + __expf(-1.5957691216f * u)) * g1;
                    if (!(lr & 1))
                        ((bf16*)Cv)[row * (long)ldc + (col >> 1)] =
                            __float2bfloat16(act);
                }
            }
        }
    }
}

// ---------------------------------------------------------------------------
// 256x256 tile, BK=64, 512 threads = 8 waves (2M x 4N), per-wave C = 128x64.
// Deep-pipelined schedule (guide §5 8-phase template, T1+T2+T3+T4+T5):
//   4 phases per K-tile (one 64x32 C-quadrant each, 16 MFMA), double-buffered
//   LDS (2 x 32KB A + 2 x 32KB B = 128 KiB), XOR chunk-swizzle (chunk^row&7)
//   applied on BOTH the pre-swizzled global source of global_load_lds and the
//   ds_read_b128 address. Prefetch of K-tile t+2 is issued in phases 2 (B) and
//   3 (A) of iteration t -- after the barrier following the last read of that
//   buffer, so staging never races reads. vmcnt(8) (never 0) in the main loop
//   keeps 8 loads in flight across barriers. Raw s_barrier (no waitcnt drain)
//   + empty asm memory fences pin compiler memory ordering; sched_barrier(0)
//   after each lgkmcnt(0) stops MFMA hoisting (rule #18).
// ---------------------------------------------------------------------------
__global__ __launch_bounds__(512, 2)
void gemm256(const bf16* __restrict__ A, const bf16* __restrict__ Bm,
             void* __restrict__ Cv, const float* __restrict__ res,
             int K, int lda, int ldb, int ldc, int epi)
{
    __shared__ __align__(16) bf16 As[2][16384];
    __shared__ __align__(16) bf16 Bs[2][16384];

    const int num_n = gridDim.x, num_m = gridDim.y;
    const int nwg = num_n * num_m;
    int pid = blockIdx.y * num_n + blockIdx.x;
    {   // bijective XCD swizzle (m204): each XCD owns a contiguous pid range
        const int q = nwg >> 3, rr = nwg & 7;
        const int x = pid & 7, o = pid >> 3;
        pid = (x < rr ? x * (q + 1) : rr * (q + 1) + (x - rr) * q) + o;
    }
    const int GROUP = 8;
    const int band = GROUP * num_n;
    const int group_id = pid / band;
    const int first_m = group_id * GROUP;
    const int gsz = min(num_m - first_m, GROUP);
    const int in_group = pid - group_id * band;
    const int pid_m = first_m + (in_group % gsz);
    const int pid_n = in_group / gsz;

    const int tid  = threadIdx.x;
    const int lane = tid & 63, wave = tid >> 6;
    const int wm = wave >> 2, wn = wave & 3;       // 2M x 4N wave grid
    const int lr = lane & 15, lq = lane >> 4;

    const long m_blk = (long)pid_m * 256;
    const long n_blk = (long)pid_n * 256;

    // staging: thread covers row sr (0..63), chunk sc (0..7) of each 64-row
    // sweep; global source pre-swizzled so linear LDS dest ends up swizzled.
    const int sr = tid >> 3, sc = tid & 7;
    const int scs = ((sc ^ (sr & 7)) << 3);
    const bf16* Ag = A  + (m_blk + sr) * (long)lda + scs;
    const bf16* Bg = Bm + (n_blk + sr) * (long)ldb + scs;
    const long ldaS = (long)lda * 64, ldbS = (long)ldb * 64;
    const int lbase = wave * 512;   // elements; lane adds lane*16B in HW

    // fragment addressing: elem = row*64 + (chunk ^ (row&7))*8, row&7 == lr&7
    const int axr = (wm * 128 + lr) * 64;
    const int bxr = (wn * 64 + lr) * 64;
    const int ck0 = ((lq ^ (lr & 7)) << 3);        // k-step 0 chunk
    const int ck1 = (((4 + lq) ^ (lr & 7)) << 3);  // k-step 1 chunk

    f32x4 acc[8][4] = {};
    const int nt = K >> 6;

    // prologue: stage K-tiles 0 and 1 (8 loads each), wait tile0 only
    #pragma unroll
    for (int i = 0; i < 4; ++i) {
        gld_lds16(Ag + i * ldaS,      &As[0][i * 4096 + lbase]);
        gld_lds16(Bg + i * ldbS,      &Bs[0][i * 4096 + lbase]);
    }
    #pragma unroll
    for (int i = 0; i < 4; ++i) {
        gld_lds16(Ag + i * ldaS + 64, &As[1][i * 4096 + lbase]);
        gld_lds16(Bg + i * ldbS + 64, &Bs[1][i * 4096 + lbase]);
    }
    asm volatile("s_waitcnt vmcnt(8)" ::: "memory");
    __builtin_amdgcn_s_barrier();
    asm volatile("" ::: "memory");

    for (int t = 0; t < nt; ++t) {
        const bf16* Ab = As[t & 1];
        const bf16* Bb = Bs[t & 1];
        bf16* lA = (bf16*)As[t & 1];
        bf16* lB = (bf16*)Bs[t & 1];
        const long ko = (long)(t + 2) * 64;
        const bool pf = (t + 2 < nt);

        bf16x8 a0[4][2], a1[4][2], b0[2][2], b1[2][2];

        // ---- phase 0: read A[mh=0](8) + B[nh=0](4); MFMA quadrant (0,0)
        #pragma unroll
        for (int f = 0; f < 4; ++f) {
            a0[f][0] = *(const bf16x8*)&Ab[axr + f * 1024 + ck0];
            a0[f][1] = *(const bf16x8*)&Ab[axr + f * 1024 + ck1];
        }
        #pragma unroll
        for (int g = 0; g < 2; ++g) {
            b0[g][0] = *(const bf16x8*)&Bb[bxr + g * 1024 + ck0];
            b0[g][1] = *(const bf16x8*)&Bb[bxr + g * 1024 + ck1];
        }
        __builtin_amdgcn_s_barrier();
        asm volatile("s_waitcnt lgkmcnt(0)" ::: "memory");
        __builtin_amdgcn_sched_barrier(0);
        __builtin_amdgcn_s_setprio(1);
        #pragma unroll
        for (int f = 0; f < 4; ++f)
            #pragma unroll
            for (int g = 0; g < 2; ++g) {
                acc[f][g] = __builtin_amdgcn_mfma_f32_16x16x32_bf16(
                    a0[f][0], b0[g][0], acc[f][g], 0, 0, 0);
                acc[f][g] = __builtin_amdgcn_mfma_f32_16x16x32_bf16(
                    a0[f][1], b0[g][1], acc[f][g], 0, 0, 0);
            }
        __builtin_amdgcn_s_setprio(0);
        __builtin_amdgcn_s_barrier();
        asm volatile("" ::: "memory");

        // ---- phase 1: read B[nh=1](4); MFMA quadrant (0,1)
        #pragma unroll
        for (int g = 0; g < 2; ++g) {
            b1[g][0] = *(const bf16x8*)&Bb[bxr + 2048 + g * 1024 + ck0];
            b1[g][1] = *(const bf16x8*)&Bb[bxr + 2048 + g * 1024 + ck1];
        }
        __builtin_amdgcn_s_barrier();
        asm volatile("s_waitcnt lgkmcnt(0)" ::: "memory");
        __builtin_amdgcn_sched_barrier(0);
        __builtin_amdgcn_s_setprio(1);
        #pragma unroll
        for (int f = 0; f < 4; ++f)
            #pragma unroll
            for (int g = 0; g < 2; ++g) {
                acc[f][2 + g] = __builtin_amdgcn_mfma_f32_16x16x32_bf16(
                    a0[f][0], b1[g][0], acc[f][2 + g], 0, 0, 0);
                acc[f][2 + g] = __builtin_amdgcn_mfma_f32_16x16x32_bf16(
                    a0[f][1], b1[g][1], acc[f][2 + g], 0, 0, 0);
            }
        __builtin_amdgcn_s_setprio(0);
        __builtin_amdgcn_s_barrier();
        asm volatile("" ::: "memory");

        // ---- phase 2: read A[mh=1](8); stage B of tile t+2 (all B reads of
        //      this buffer completed at phase-1's trailing barrier); MFMA (1,1)
        #pragma unroll
        for (int f = 0; f < 4; ++f) {
            a1[f][0] = *(const bf16x8*)&Ab[axr + 4096 + f * 1024 + ck0];
            a1[f][1] = *(const bf16x8*)&Ab[axr + 4096 + f * 1024 + ck1];
        }
        if (pf) {
            #pragma unroll
            for (int i = 0; i < 4; ++i)
                gld_lds16(Bg + i * ldbS + ko, &lB[i * 4096 + lbase]);
        }
        __builtin_amdgcn_s_barrier();
        asm volatile("s_waitcnt lgkmcnt(0)" ::: "memory");
        __builtin_amdgcn_sched_barrier(0);
        __builtin_amdgcn_s_setprio(1);
        #pragma unroll
        for (int f = 0; f < 4; ++f)
            #pragma unroll
            for (int g = 0; g < 2; ++g) {
                acc[4 + f][2 + g] = __builtin_amdgcn_mfma_f32_16x16x32_bf16(
                    a1[f][0], b1[g][0], acc[4 + f][2 + g], 0, 0, 0);
                acc[4 + f][2 + g] = __builtin_amdgcn_mfma_f32_16x16x32_bf16(
                    a1[f][1], b1[g][1], acc[4 + f][2 + g], 0, 0, 0);
            }
        __builtin_amdgcn_s_setprio(0);
        __builtin_amdgcn_s_barrier();
        asm volatile("" ::: "memory");

        // ---- phase 3: stage A of tile t+2 (A reads done at phase-2 barrier);
        //      MFMA (1,0); counted vmcnt -- tile t+1 confirmed, t+2 in flight
        if (pf) {
            #pragma unroll
            for (int i = 0; i < 4; ++i)
                gld_lds16(Ag + i * ldaS + ko, &lA[i * 4096 + lbase]);
        }
        __builtin_amdgcn_s_setprio(1);
        #pragma unroll
        for (int f = 0; f < 4; ++f)
            #pragma unroll
            for (int g = 0; g < 2; ++g) {
                acc[4 + f][g] = __builtin_amdgcn_mfma_f32_16x16x32_bf16(
                    a1[f][0], b0[g][0], acc[4 + f][g], 0, 0, 0);
                acc[4 + f][g] = __builtin_amdgcn_mfma_f32_16x16x32_bf16(
                    a1[f][1], b0[g][1], acc[4 + f][g], 0, 0, 0);
            }
        __builtin_amdgcn_s_setprio(0);
        if (pf) asm volatile("s_waitcnt vmcnt(8)" ::: "memory");
        else    asm volatile("s_waitcnt vmcnt(0)" ::: "memory");
        __builtin_amdgcn_s_barrier();
        asm volatile("" ::: "memory");
    }

    // epilogue: col = lane&15, row = (lane>>4)*4 + reg
    #pragma unroll
    for (int m = 0; m < 8; ++m) {
        #pragma unroll
        for (int n = 0; n < 4; ++n) {
            const long col = n_blk + wn * 64 + n * 16 + lr;
            #pragma unroll
            for (int r = 0; r < 4; ++r) {
                const long row = m_blk + wm * 128 + m * 16 + lq * 4 + r;
                const float v = acc[m][n][r];
                if (epi == 0) {
                    ((bf16*)Cv)[row * (long)ldc + col] = __float2bfloat16(v);
                } else if (epi == 1) {
                    ((float*)Cv)[row * (long)ldc + col] = v;
                } else if (epi == 2) {
                    ((float*)Cv)[row * (long)ldc + col] =
                        v + res[row * (long)ldc + col];
                } else {
                    const float pv = __shfl_xor(v, 1, 64);
                    const float g0 = (lr & 1) ? pv : v;
                    const float g1 = (lr & 1) ? v : pv;
                    const float u = g0 + 0.044715f * g0 * g0 * g0;
                    const float act = g0 / (1.f + __expf(-1.5957691216f * u)) * g1;
                    if (!(lr & 1))
                        ((bf16*)Cv)[row * (long)ldc + (col >> 1)] =
                            __float2bfloat16(act);
                }
            }
        }
    }
}

// ---------------------------------------------------------------------------
// fp32 -> bf16 transpose. in: (R,C) ld=ldin; out row = c*rowMul, ld=ldout.
// ---------------------------------------------------------------------------
__global__ __launch_bounds__(256)
void transpose_f2b(const float* __restrict__ in, bf16* __restrict__ out,
                   int ldin, int ldout, long inB, long outB, int rowMul)
{
    __shared__ float tile[32][33];
    in  += (long)blockIdx.z * inB;
    out += (long)blockIdx.z * outB;
    const int r0 = blockIdx.y * 32, c0 = blockIdx.x * 32;
    const int tx = threadIdx.x & 31, ty = threadIdx.x >> 5;
    #pragma unroll
    for (int i = 0; i < 32; i += 8)
        tile[ty + i][tx] = in[(long)(r0 + ty + i) * ldin + c0 + tx];
    __syncthreads();
    #pragma unroll
    for (int i = 0; i < 32; i += 8)
        out[(long)(c0 + ty + i) * rowMul * ldout + r0 + tx] =
            __float2bfloat16(tile[tx][ty + i]);
}

// bf16 -> bf16 transpose (for V)
__global__ __launch_bounds__(256)
void transpose_b2b(const bf16* __restrict__ in, bf16* __restrict__ out,
                   int ldin, int ldout, long inB, long outB)
{
    __shared__ bf16 tile[32][33];
    in  += (long)blockIdx.z * inB;
    out += (long)blockIdx.z * outB;
    const int r0 = blockIdx.y * 32, c0 = blockIdx.x * 32;
    const int tx = threadIdx.x & 31, ty = threadIdx.x >> 5;
    #pragma unroll
    for (int i = 0; i < 32; i += 8)
        tile[ty + i][tx] = in[(long)(r0 + ty + i) * ldin + c0 + tx];
    __syncthreads();
    #pragma unroll
    for (int i = 0; i < 32; i += 8)
        out[(long)(c0 + ty + i) * ldout + r0 + tx] = tile[tx][ty + i];
}

// ---------------------------------------------------------------------------
__global__ __launch_bounds__(256)
void rmsnorm_k(const float* __restrict__ x, const float* __restrict__ scale,
               bf16* __restrict__ out)
{
    const long row = blockIdx.x;
    const float* xr = x + row * 2048;
    const int tid = threadIdx.x;
    const float4 a = ((const float4*)xr)[tid];
    const float4 b = ((const float4*)xr)[tid + 256];
    float ss = a.x*a.x + a.y*a.y + a.z*a.z + a.w*a.w
             + b.x*b.x + b.y*b.y + b.z*b.z + b.w*b.w;
    for (int o = 32; o; o >>= 1) ss += __shfl_down(ss, o, 64);
    __shared__ float red[4];
    const int lane = tid & 63, wave = tid >> 6;
    if (lane == 0) red[wave] = ss;
    __syncthreads();
    const float inv = rsqrtf((red[0] + red[1] + red[2] + red[3]) * (1.f / 2048.f) + 1e-6f);
    const float4 s0 = ((const float4*)scale)[tid];
    const float4 s1 = ((const float4*)scale)[tid + 256];
    bf16* orow = out + row * 2048;
    const int i0 = tid * 4, i1 = 1024 + tid * 4;
    orow[i0 + 0] = __float2bfloat16(a.x * inv * (1.f + s0.x));
    orow[i0 + 1] = __float2bfloat16(a.y * inv * (1.f + s0.y));
    orow[i0 + 2] = __float2bfloat16(a.z * inv * (1.f + s0.z));
    orow[i0 + 3] = __float2bfloat16(a.w * inv * (1.f + s0.w));
    orow[i1 + 0] = __float2bfloat16(b.x * inv * (1.f + s1.x));
    orow[i1 + 1] = __float2bfloat16(b.y * inv * (1.f + s1.y));
    orow[i1 + 2] = __float2bfloat16(b.z * inv * (1.f + s1.z));
    orow[i1 + 3] = __float2bfloat16(b.w * inv * (1.f + s1.w));
}

// ---------------------------------------------------------------------------
// RoPE in-place on qkv rows (2560 wide): heads 0..7 = q (scaled by H^-0.5),
// head 8 = k. half = 128.
// ---------------------------------------------------------------------------
__global__ __launch_bounds__(256)
void rope_k(bf16* __restrict__ qkv, const int* __restrict__ positions)
{
    const long row = blockIdx.x;
    const float pos = (float)positions[row];
    bf16* rp = qkv + row * 2560;
    for (int w = threadIdx.x; w < 1152; w += 256) {
        const int head = w >> 7;
        const int j = w & 127;
        const int base = head * 256;
        const float x1 = __bfloat162float(rp[base + j]);
        const float x2 = __bfloat162float(rp[base + 128 + j]);
        const float ts = powf(10000.f, (float)j * (1.f / 128.f));
        const float rad = pos / ts;
        const float s = sinf(rad), c = cosf(rad);
        const float sc = (head < 8) ? 0.0625f : 1.0f;
        rp[base + j]       = __float2bfloat16((x1 * c - x2 * s) * sc);
        rp[base + 128 + j] = __float2bfloat16((x2 * c + x1 * s) * sc);
    }
}

// ---------------------------------------------------------------------------
// Causal softmax, bf16 in / bf16 out, row length 2048, valid s <= t.
// ---------------------------------------------------------------------------
__global__ __launch_bounds__(256)
void softmax_causal(const bf16* __restrict__ logits, bf16* __restrict__ probs)
{
    const int t = blockIdx.x;
    const long rowid = (long)blockIdx.y * 2048 + t;
    const bf16* lrow = logits + rowid * 2048;
    bf16* prow = probs + rowid * 2048;
    const int tid = threadIdx.x;
    const bf16x8 raw = *(const bf16x8*)(lrow + tid * 8);
    float va[8];
    #pragma unroll
    for (int i = 0; i < 8; ++i)
        va[i] = __uint_as_float(((unsigned)(unsigned short)raw[i]) << 16);
    const int s0 = tid * 8;

    float mx = -3.0e38f;
    #pragma unroll
    for (int i = 0; i < 8; ++i) if (s0 + i <= t) mx = fmaxf(mx, va[i]);
    for (int o = 32; o; o >>= 1) mx = fmaxf(mx, __shfl_down(mx, o, 64));
    __shared__ float red[4];
    const int lane = tid & 63, wave = tid >> 6;
    if (lane == 0) red[wave] = mx;
    __syncthreads();
    mx = fmaxf(fmaxf(red[0], red[1]), fmaxf(red[2], red[3]));
    __syncthreads();

    float e[8]; float sum = 0.f;
    #pragma unroll
    for (int i = 0; i < 8; ++i) {
        e[i] = (s0 + i <= t) ? __expf(va[i] - mx) : 0.f;
        sum += e[i];
    }
    for (int o = 32; o; o >>= 1) sum += __shfl_down(sum, o, 64);
    if (lane == 0) red[wave] = sum;
    __syncthreads();
    sum = red[0] + red[1] + red[2] + red[3];
    const float inv = 1.f / sum;
    #pragma unroll
    for (int i = 0; i < 8; ++i) prow[s0 + i] = __float2bfloat16(e[i] * inv);
}

// ---------------------------------------------------------------------------
static inline void launch_gemm(const bf16* A, const bf16* Bm, void* C,
                               const float* res, int M, int N, int K,
                               int lda, int ldb, int ldc,
                               long sAb, long sAn, long sBb, long sBn,
                               long sCb, long sCn, int nOuter, int nInner,
                               int epi, hipStream_t s)
{
    dim3 g(N / 128, M / 128, nOuter * nInner);
    gemm_bt<<<g, dim3(256), 0, s>>>(A, Bm, C, res, K, lda, ldb, ldc,
                                    sAb, sAn, sBb, sBn, sCb, sCn, nInner, epi);
}

static inline void launch_gemm256(const bf16* A, const bf16* Bm, void* C,
                                  const float* res, int M, int N, int K,
                                  int lda, int ldb, int ldc, int epi,
                                  hipStream_t s)
{
    dim3 g(N / 256, M / 256, 1);
    gemm256<<<g, dim3(512), 0, s>>>(A, Bm, C, res, K, lda, ldb, ldc, epi);
}

extern "C" void kernel_launch(void* const* d_in, const int* in_sizes, int n_in,
                              void* d_out, int out_size, void* d_ws, size_t ws_size,
                              hipStream_t stream)
{
    const float* x          = (const float*)d_in[0];
    const int*   positions  = (const int*)d_in[1];
    const float* q_w        = (const float*)d_in[3];
    const float* kv_w       = (const float*)d_in[4];
    const float* attn_vec_w = (const float*)d_in[5];
    const float* gating_w   = (const float*)d_in[6];
    const float* linear_w   = (const float*)d_in[7];
    const float* pre_attn_s = (const float*)d_in[8];
    const float* pre_ffw_s  = (const float*)d_in[9];
    float* out = (float*)d_out;

    char* p = (char*)d_ws;
    auto alloc = [&](size_t bytes) { char* r = p; p += (bytes + 255) & ~(size_t)255; return r; };
    bf16*  Wqkv   = (bf16*)alloc(2560UL * 2048 * 2);     // [r][d]
    bf16*  Wo     = (bf16*)alloc(2048UL * 2048 * 2);     // [d][nh]
    bf16*  Wg     = (bf16*)alloc(32768UL * 2048 * 2);    // interleaved [2f+c][d]
    bf16*  Wl     = (bf16*)alloc(2048UL * 16384 * 2);    // [d][f]
    bf16*  h      = (bf16*)alloc(4096UL * 2048 * 2);
    bf16*  qkv    = (bf16*)alloc(4096UL * 2560 * 2);
    bf16*  vt     = (bf16*)alloc(2UL * 256 * 2048 * 2);
    float* xmid   = (float*)alloc(4096UL * 2048 * 4);
    bf16*  enc    = (bf16*)alloc(4096UL * 2048 * 2);
    bf16*  logits = (bf16*)alloc(16UL * 2048 * 2048 * 2);
    bf16*  probs  = (bf16*)alloc(16UL * 2048 * 2048 * 2);
    bf16*  acts   = logits;  // reuse: logits dead after softmax
    if ((size_t)(p - (char*)d_ws) > ws_size) return;

    // ---- weight prep ----
    transpose_f2b<<<dim3(8, 64, 8), 256, 0, stream>>>(q_w, Wqkv, 256, 2048,
                                                      2048L * 256, 256L * 2048, 1);
    transpose_f2b<<<dim3(8, 64, 2), 256, 0, stream>>>(kv_w, Wqkv + 2048L * 2048,
                                                      256, 2048, 2048L * 256, 256L * 2048, 1);
    transpose_f2b<<<dim3(64, 64, 1), 256, 0, stream>>>(attn_vec_w, Wo, 2048, 2048, 0, 0, 1);
    // gating: interleave g0/g1 -> row 2f+c  (outB = one row, rowMul = 2)
    transpose_f2b<<<dim3(512, 64, 2), 256, 0, stream>>>(gating_w, Wg, 16384, 2048,
                                                        2048L * 16384, 2048, 2);
    transpose_f2b<<<dim3(64, 512, 1), 256, 0, stream>>>(linear_w, Wl, 2048, 16384, 0, 0, 1);

    // ---- attention ----
    rmsnorm_k<<<4096, 256, 0, stream>>>(x, pre_attn_s, h);
    launch_gemm(h, Wqkv, qkv, nullptr, 4096, 2560, 2048, 2048, 2048, 2560,
                0, 0, 0, 0, 0, 0, 1, 1, 0, stream);
    rope_k<<<4096, 256, 0, stream>>>(qkv, positions);
    transpose_b2b<<<dim3(8, 64, 2), 256, 0, stream>>>(qkv + 2304, vt, 2560, 2048,
                                                      2048L * 2560, 256L * 2048);
    // logits[b,n,t,s] = q.k  (bf16 out)
    launch_gemm(qkv, qkv + 2048, logits, nullptr, 2048, 2048, 256, 2560, 2560, 2048,
                2048L * 2560, 256, 2048L * 2560, 0,
                8L * 2048 * 2048, 2048L * 2048, 2, 8, 0, stream);
    softmax_causal<<<dim3(2048, 16), 256, 0, stream>>>(logits, probs);
    launch_gemm(probs, vt, enc, nullptr, 2048, 256, 2048, 2048, 2048, 2048,
                8L * 2048 * 2048, 2048L * 2048, 256L * 2048, 0,
                2048L * 2048, 256, 2, 8, 0, stream);
    launch_gemm(enc, Wo, xmid, x, 4096, 2048, 2048, 2048, 2048, 2048,
                0, 0, 0, 0, 0, 0, 1, 1, 2, stream);

    // ---- FFW ----
    rmsnorm_k<<<4096, 256, 0, stream>>>(xmid, pre_ffw_s, h);
    // fused gating + gelu-gate (256^2 deep-pipelined): acts 4096x16384 bf16
    launch_gemm256(h, Wg, acts, nullptr, 4096, 32768, 2048, 2048, 2048, 16384,
                   3, stream);
    // down-proj + residual (256^2 deep-pipelined)
    launch_gemm256(acts, Wl, out, xmid, 4096, 2048, 16384, 16384, 16384, 2048,
                   2, stream);
}